// Round 1
// baseline (2675.208 us; speedup 1.0000x reference)
//
#include <hip/hip_runtime.h>
#include <math.h>

#define FM 32
#define N_EDGES 3200000
#define VAR_COUNT 100000
#define CONST_COUNT 50000
#define LN_EPS 1e-5f

__global__ void fill_ones(float* __restrict__ p, int n) {
    int i = blockIdx.x * blockDim.x + threadIdx.x;
    if (i < n) p[i] = 1.0f;
}

// Constraint embedding: scalar -> 64 (relu) -> 32, LayerNorm.
// One 64-lane group per row; 4 rows per 256-thread block.
__global__ __launch_bounds__(256) void pc_mlp(
    const float* __restrict__ cond,
    const float* __restrict__ W1, const float* __restrict__ b1,
    const float* __restrict__ W2, const float* __restrict__ b2,
    float* __restrict__ dst, int nrows) {
    __shared__ float sW2[64 * 32];
    __shared__ float sh[4][64];
    for (int i = threadIdx.x; i < 64 * 32; i += 256) sW2[i] = W2[i];
    __syncthreads();
    int g = threadIdx.x >> 6, l = threadIdx.x & 63;
    int row = blockIdx.x * 4 + g;
    float c = (row < nrows) ? cond[row] : 0.0f;
    sh[g][l] = fmaxf(c * W1[l] + b1[l], 0.0f);
    __syncthreads();
    if (row < nrows && l < 32) {
        float y = b2[l];
#pragma unroll
        for (int k = 0; k < 64; ++k) y += sh[g][k] * sW2[k * 32 + l];
        float s = y;
        for (int m = 16; m; m >>= 1) s += __shfl_xor(s, m);
        float mu = s * (1.0f / 32.0f);
        float d = y - mu;
        float v = d * d;
        for (int m = 16; m; m >>= 1) v += __shfl_xor(v, m);
        dst[row * 32 + l] = d * rsqrtf(v * (1.0f / 32.0f) + LN_EPS);
    }
}

// Gather src[src_idx[e]] * ev[e], atomically add into dst[dst_idx[e]].
// 32 lanes per edge (one per feature).
__global__ __launch_bounds__(256) void scatter_edges(
    const int* __restrict__ src_idx, const int* __restrict__ dst_idx,
    const float* __restrict__ ev, const float* __restrict__ src,
    float* __restrict__ dst, int n_edges) {
    int e = blockIdx.x * 8 + (threadIdx.x >> 5);
    int f = threadIdx.x & 31;
    if (e >= n_edges) return;
    int is = src_idx[e];
    int id = dst_idx[e];
    float w = ev[e];
    atomicAdd(&dst[id * 32 + f], src[is * 32 + f] * w);
}

// Generic MLP + LayerNorm: IN = NSEG*32 -> 64 (relu) -> 32, LN.
// Sources are NSEG separate row-major [nrows,32] arrays (concat semantics).
// In-place safe: each row's input is staged into LDS before output write.
template <int NSEG>
__global__ __launch_bounds__(256) void mlp_ln(
    const float* __restrict__ s0, const float* __restrict__ s1,
    const float* __restrict__ s2,
    const float* __restrict__ W1, const float* __restrict__ b1,
    const float* __restrict__ W2, const float* __restrict__ b2,
    float* __restrict__ dst, int nrows) {
    constexpr int IN = NSEG * 32;
    __shared__ float sW1[IN * 64];
    __shared__ float sW2[64 * 32];
    __shared__ float sx[4][IN];
    __shared__ float sh[4][64];
    for (int i = threadIdx.x; i < IN * 64; i += 256) sW1[i] = W1[i];
    for (int i = threadIdx.x; i < 64 * 32; i += 256) sW2[i] = W2[i];
    int g = threadIdx.x >> 6, l = threadIdx.x & 63;
    int row = blockIdx.x * 4 + g;
    __syncthreads();
    if (row < nrows) {
#pragma unroll
        for (int i = l; i < IN; i += 64) {
            const float* s = (i < 32) ? s0 : (i < 64) ? s1 : s2;
            sx[g][i] = s[row * 32 + (i & 31)];
        }
    }
    __syncthreads();
    float acc = b1[l];
#pragma unroll
    for (int k = 0; k < IN; ++k) acc += sx[g][k] * sW1[k * 64 + l];
    sh[g][l] = fmaxf(acc, 0.0f);
    __syncthreads();
    if (row < nrows && l < 32) {
        float y = b2[l];
#pragma unroll
        for (int k = 0; k < 64; ++k) y += sh[g][k] * sW2[k * 32 + l];
        float s = y;
        for (int m = 16; m; m >>= 1) s += __shfl_xor(s, m);
        float mu = s * (1.0f / 32.0f);
        float d = y - mu;
        float v = d * d;
        for (int m = 16; m; m >>= 1) v += __shfl_xor(v, m);
        dst[row * 32 + l] = d * rsqrtf(v * (1.0f / 32.0f) + LN_EPS);
    }
}

// Output head: 32 -> 64 (relu) -> 16, sigmoid. No LN.
__global__ __launch_bounds__(256) void out_mlp(
    const float* __restrict__ x,
    const float* __restrict__ W1, const float* __restrict__ b1,
    const float* __restrict__ W2, const float* __restrict__ b2,
    float* __restrict__ dst, int nrows) {
    __shared__ float sW1[32 * 64];
    __shared__ float sW2[64 * 16];
    __shared__ float sx[4][32];
    __shared__ float sh[4][64];
    for (int i = threadIdx.x; i < 32 * 64; i += 256) sW1[i] = W1[i];
    for (int i = threadIdx.x; i < 64 * 16; i += 256) sW2[i] = W2[i];
    int g = threadIdx.x >> 6, l = threadIdx.x & 63;
    int row = blockIdx.x * 4 + g;
    __syncthreads();
    if (row < nrows && l < 32) sx[g][l] = x[row * 32 + l];
    __syncthreads();
    float acc = b1[l];
#pragma unroll
    for (int k = 0; k < 32; ++k) acc += sx[g][k] * sW1[k * 64 + l];
    sh[g][l] = fmaxf(acc, 0.0f);
    __syncthreads();
    if (row < nrows && l < 16) {
        float y = b2[l];
#pragma unroll
        for (int k = 0; k < 64; ++k) y += sh[g][k] * sW2[k * 16 + l];
        dst[row * 16 + l] = 1.0f / (1.0f + expf(-y));
    }
}

extern "C" void kernel_launch(void* const* d_in, const int* in_sizes, int n_in,
                              void* d_out, int out_size, void* d_ws, size_t ws_size,
                              hipStream_t stream) {
    const int*   edge_var   = (const int*)d_in[0];
    const int*   edge_const = (const int*)d_in[1];
    const float* edge_val   = (const float*)d_in[2];
    const float* cond       = (const float*)d_in[3];
    // d_in[4], d_in[5]: var_count/const_count scalars (compile-time constants here)
    const float* pc_W1 = (const float*)d_in[6];
    const float* pc_b1 = (const float*)d_in[7];
    const float* pc_W2 = (const float*)d_in[8];
    const float* pc_b2 = (const float*)d_in[9];
    const float* cu_W1 = (const float*)d_in[10];
    const float* cu_b1 = (const float*)d_in[11];
    const float* cu_W2 = (const float*)d_in[12];
    const float* cu_b2 = (const float*)d_in[13];
    const float* vu_W1 = (const float*)d_in[14];
    const float* vu_b1 = (const float*)d_in[15];
    const float* vu_W2 = (const float*)d_in[16];
    const float* vu_b2 = (const float*)d_in[17];
    const float* out_W1 = (const float*)d_in[18];
    const float* out_b1 = (const float*)d_in[19];
    const float* out_W2 = (const float*)d_in[20];
    const float* out_b2 = (const float*)d_in[21];

    float* ws   = (float*)d_ws;
    float* emb  = ws;                          // 50000*32
    float* cons = emb  + CONST_COUNT * FM;     // 50000*32
    float* vars = cons + CONST_COUNT * FM;     // 100000*32
    float* msg  = vars + VAR_COUNT * FM;       // 100000*32 (v2c uses first half)

    // variables = ones
    fill_ones<<<(VAR_COUNT * FM + 255) / 256, 256, 0, stream>>>(vars, VAR_COUNT * FM);
    // emb = mlp_ln(conditions)
    pc_mlp<<<(CONST_COUNT + 3) / 4, 256, 0, stream>>>(cond, pc_W1, pc_b1, pc_W2, pc_b2,
                                                      emb, CONST_COUNT);
    // constraints = emb
    hipMemcpyAsync(cons, emb, CONST_COUNT * FM * sizeof(float),
                   hipMemcpyDeviceToDevice, stream);

    for (int pass = 0; pass < 3; ++pass) {
        // v2c = segment_sum(variables[edge_var]*ev, edge_const)
        hipMemsetAsync(msg, 0, CONST_COUNT * FM * sizeof(float), stream);
        scatter_edges<<<N_EDGES / 8, 256, 0, stream>>>(edge_var, edge_const, edge_val,
                                                       vars, msg, N_EDGES);
        // constraints = mlp_ln([constraints, emb, v2c])
        mlp_ln<3><<<(CONST_COUNT + 3) / 4, 256, 0, stream>>>(
            cons, emb, msg, cu_W1, cu_b1, cu_W2, cu_b2, cons, CONST_COUNT);
        // c2v = segment_sum(constraints[edge_const]*ev, edge_var)
        hipMemsetAsync(msg, 0, VAR_COUNT * FM * sizeof(float), stream);
        scatter_edges<<<N_EDGES / 8, 256, 0, stream>>>(edge_const, edge_var, edge_val,
                                                       cons, msg, N_EDGES);
        // variables = mlp_ln([variables, c2v])
        mlp_ln<2><<<(VAR_COUNT + 3) / 4, 256, 0, stream>>>(
            vars, msg, nullptr, vu_W1, vu_b1, vu_W2, vu_b2, vars, VAR_COUNT);
    }

    // out = sigmoid(relu(vars @ W1 + b1) @ W2 + b2)
    out_mlp<<<(VAR_COUNT + 3) / 4, 256, 0, stream>>>(vars, out_W1, out_b1, out_W2, out_b2,
                                                     (float*)d_out, VAR_COUNT);
}

// Round 2
// 1687.344 us; speedup vs baseline: 1.5855x; 1.5855x over previous
//
#include <hip/hip_runtime.h>
#include <math.h>

#define FM 32
#define N_EDGES 3200000
#define VAR_COUNT 100000
#define CONST_COUNT 50000
#define LN_EPS 1e-5f

static __device__ __forceinline__ float warp_sum32(float v) {
#pragma unroll
    for (int m = 16; m; m >>= 1) v += __shfl_xor(v, m);
    return v;
}

__global__ void fill_ones(float* __restrict__ p, int n) {
    int i = blockIdx.x * 256 + threadIdx.x;
    if (i < n) p[i] = 1.0f;
}

// ---------------- CSR construction (counting sort by destination) ----------------

__global__ __launch_bounds__(256) void histo(
    const int* __restrict__ e_var, const int* __restrict__ e_const,
    int* __restrict__ cnt_v, int* __restrict__ cnt_c, int n) {
    int i = blockIdx.x * 256 + threadIdx.x;
    if (i < n) {
        atomicAdd(&cnt_c[e_const[i]], 1);
        atomicAdd(&cnt_v[e_var[i]], 1);
    }
}

// chunk = 1024 elems per block (256 threads x 4). In-place safe.
__global__ __launch_bounds__(256) void scan1(const int* __restrict__ in, int* __restrict__ out,
                                             int* __restrict__ bsum, int n) {
    __shared__ int ls[256];
    int t = threadIdx.x;
    int idx = blockIdx.x * 1024 + t * 4;
    int a0 = (idx + 0 < n) ? in[idx + 0] : 0;
    int a1 = (idx + 1 < n) ? in[idx + 1] : 0;
    int a2 = (idx + 2 < n) ? in[idx + 2] : 0;
    int a3 = (idx + 3 < n) ? in[idx + 3] : 0;
    int tsum = a0 + a1 + a2 + a3;
    ls[t] = tsum;
    __syncthreads();
    for (int off = 1; off < 256; off <<= 1) {
        int v = (t >= off) ? ls[t - off] : 0;
        __syncthreads();
        ls[t] += v;
        __syncthreads();
    }
    int excl = ls[t] - tsum;
    if (idx + 0 < n) out[idx + 0] = excl;
    if (idx + 1 < n) out[idx + 1] = excl + a0;
    if (idx + 2 < n) out[idx + 2] = excl + a0 + a1;
    if (idx + 3 < n) out[idx + 3] = excl + a0 + a1 + a2;
    if (t == 255) bsum[blockIdx.x] = ls[255];
}

__global__ __launch_bounds__(256) void scan2(int* __restrict__ b, int nb) {
    __shared__ int ls[256];
    int t = threadIdx.x;
    int v0 = (t < nb) ? b[t] : 0;
    ls[t] = v0;
    __syncthreads();
    for (int off = 1; off < 256; off <<= 1) {
        int v = (t >= off) ? ls[t - off] : 0;
        __syncthreads();
        ls[t] += v;
        __syncthreads();
    }
    if (t < nb) b[t] = ls[t] - v0;  // exclusive
}

__global__ __launch_bounds__(256) void scan3(int* __restrict__ offs, int* __restrict__ cur,
                                             const int* __restrict__ bsum, int n, int total) {
    int i = blockIdx.x * 256 + threadIdx.x;
    if (i < n) {
        int v = offs[i] + bsum[i >> 10];
        offs[i] = v;
        cur[i] = v;
    } else if (i == n) {
        offs[n] = total;
    }
}

__global__ __launch_bounds__(256) void fill_csr(
    const int* __restrict__ e_var, const int* __restrict__ e_const, const float* __restrict__ e_val,
    int* __restrict__ cur_c, int* __restrict__ cur_v,
    int2* __restrict__ csr_c, int2* __restrict__ csr_v, int n) {
    int i = blockIdx.x * 256 + threadIdx.x;
    if (i >= n) return;
    int v = e_var[i], c = e_const[i];
    int wbits = __float_as_int(e_val[i]);
    int pc = atomicAdd(&cur_c[c], 1);
    csr_c[pc] = make_int2(v, wbits);
    int pv = atomicAdd(&cur_v[v], 1);
    csr_v[pv] = make_int2(c, wbits);
}

// ---------------- segment sum via gather: dst[r] = sum_j src[idx_j]*w_j ----------------

__global__ __launch_bounds__(256) void seg_gather(
    const int* __restrict__ offs, const int2* __restrict__ csr,
    const float* __restrict__ src, float* __restrict__ dst, int nrows) {
    int g = threadIdx.x >> 5, f = threadIdx.x & 31;
    int row = blockIdx.x * 8 + g;
    if (row >= nrows) return;
    int j = offs[row], j1 = offs[row + 1];
    float acc0 = 0.0f, acc1 = 0.0f;
    for (; j + 2 <= j1; j += 2) {
        int2 a = csr[j];
        int2 b = csr[j + 1];
        acc0 = fmaf(src[(size_t)a.x * FM + f], __int_as_float(a.y), acc0);
        acc1 = fmaf(src[(size_t)b.x * FM + f], __int_as_float(b.y), acc1);
    }
    if (j < j1) {
        int2 a = csr[j];
        acc0 = fmaf(src[(size_t)a.x * FM + f], __int_as_float(a.y), acc0);
    }
    dst[(size_t)row * FM + f] = acc0 + acc1;
}

// ---------------- fallback atomic scatter (used only if ws too small) ----------------

__global__ __launch_bounds__(256) void scatter_edges(
    const int* __restrict__ src_idx, const int* __restrict__ dst_idx,
    const float* __restrict__ ev, const float* __restrict__ src,
    float* __restrict__ dst, int n_edges) {
    int e = blockIdx.x * 8 + (threadIdx.x >> 5);
    int f = threadIdx.x & 31;
    if (e >= n_edges) return;
    atomicAdd(&dst[(size_t)dst_idx[e] * FM + f], src[(size_t)src_idx[e] * FM + f] * ev[e]);
}

// ---------------- MLP + LayerNorm kernels ----------------

// scalar -> 64 (relu) -> 32, LN. Wave-local groups, grid-stride.
__global__ __launch_bounds__(256) void pc_mlp(
    const float* __restrict__ cond,
    const float* __restrict__ W1, const float* __restrict__ b1,
    const float* __restrict__ W2, const float* __restrict__ b2,
    float* __restrict__ dst, int nrows) {
    __shared__ float sW2[64 * FM];
    __shared__ float sh[4][64];
    for (int i = threadIdx.x; i < 64 * FM; i += 256) sW2[i] = W2[i];
    int g = threadIdx.x >> 6, l = threadIdx.x & 63, l32 = l & 31, half = l >> 5;
    float w1l = W1[l], b1l = b1[l], b2l = b2[l32];
    __syncthreads();
    for (int row = blockIdx.x * 4 + g; row < nrows; row += gridDim.x * 4) {
        float c = cond[row];
        sh[g][l] = fmaxf(fmaf(c, w1l, b1l), 0.0f);
        float y = 0.0f;
#pragma unroll
        for (int k = 0; k < 32; k += 4) {
            float4 hv = *(const float4*)&sh[g][half * 32 + k];
            y = fmaf(hv.x, sW2[(half * 32 + k + 0) * FM + l32], y);
            y = fmaf(hv.y, sW2[(half * 32 + k + 1) * FM + l32], y);
            y = fmaf(hv.z, sW2[(half * 32 + k + 2) * FM + l32], y);
            y = fmaf(hv.w, sW2[(half * 32 + k + 3) * FM + l32], y);
        }
        y += __shfl_xor(y, 32);
        y += b2l;
        float s = warp_sum32(y);
        float mu = s * (1.0f / 32.0f);
        float d = y - mu;
        float v = warp_sum32(d * d);
        if (half == 0) dst[(size_t)row * FM + l32] = d * rsqrtf(v * (1.0f / 32.0f) + LN_EPS);
    }
}

// IN = NSEG*32 -> 64 (relu) -> 32, LN. In-place safe per row.
template <int NSEG>
__global__ __launch_bounds__(256) void mlp_ln(
    const float* __restrict__ s0, const float* __restrict__ s1,
    const float* __restrict__ s2,
    const float* __restrict__ W1, const float* __restrict__ b1,
    const float* __restrict__ W2, const float* __restrict__ b2,
    float* __restrict__ dst, int nrows) {
    constexpr int IN = NSEG * FM;
    __shared__ float sW1[IN * 64];
    __shared__ float sW2[64 * FM];
    __shared__ float sx[4][IN];
    __shared__ float sh[4][64];
    for (int i = threadIdx.x; i < IN * 64; i += 256) sW1[i] = W1[i];
    for (int i = threadIdx.x; i < 64 * FM; i += 256) sW2[i] = W2[i];
    int g = threadIdx.x >> 6, l = threadIdx.x & 63, l32 = l & 31, half = l >> 5;
    float b1l = b1[l], b2l = b2[l32];
    __syncthreads();
    for (int row = blockIdx.x * 4 + g; row < nrows; row += gridDim.x * 4) {
#pragma unroll
        for (int i = l; i < IN; i += 64) {
            const float* s = (i < 32) ? s0 : (i < 64) ? s1 : s2;
            sx[g][i] = s[(size_t)row * FM + (i & 31)];
        }
        float acc = b1l;
#pragma unroll
        for (int k = 0; k < IN; k += 4) {
            float4 xv = *(const float4*)&sx[g][k];
            acc = fmaf(xv.x, sW1[(k + 0) * 64 + l], acc);
            acc = fmaf(xv.y, sW1[(k + 1) * 64 + l], acc);
            acc = fmaf(xv.z, sW1[(k + 2) * 64 + l], acc);
            acc = fmaf(xv.w, sW1[(k + 3) * 64 + l], acc);
        }
        sh[g][l] = fmaxf(acc, 0.0f);
        float y = 0.0f;
#pragma unroll
        for (int k = 0; k < 32; k += 4) {
            float4 hv = *(const float4*)&sh[g][half * 32 + k];
            y = fmaf(hv.x, sW2[(half * 32 + k + 0) * FM + l32], y);
            y = fmaf(hv.y, sW2[(half * 32 + k + 1) * FM + l32], y);
            y = fmaf(hv.z, sW2[(half * 32 + k + 2) * FM + l32], y);
            y = fmaf(hv.w, sW2[(half * 32 + k + 3) * FM + l32], y);
        }
        y += __shfl_xor(y, 32);
        y += b2l;
        float s = warp_sum32(y);
        float mu = s * (1.0f / 32.0f);
        float d = y - mu;
        float v = warp_sum32(d * d);
        if (half == 0) dst[(size_t)row * FM + l32] = d * rsqrtf(v * (1.0f / 32.0f) + LN_EPS);
    }
}

// 32 -> 64 (relu) -> 16, sigmoid. 4-way k-split for layer 2.
__global__ __launch_bounds__(256) void out_mlp(
    const float* __restrict__ x,
    const float* __restrict__ W1, const float* __restrict__ b1,
    const float* __restrict__ W2, const float* __restrict__ b2,
    float* __restrict__ dst, int nrows) {
    __shared__ float sW1[FM * 64];
    __shared__ float sW2[64 * 16];
    __shared__ float sx[4][FM];
    __shared__ float sh[4][64];
    for (int i = threadIdx.x; i < FM * 64; i += 256) sW1[i] = W1[i];
    for (int i = threadIdx.x; i < 64 * 16; i += 256) sW2[i] = W2[i];
    int g = threadIdx.x >> 6, l = threadIdx.x & 63;
    int o = l & 15, q = l >> 4;
    float b1l = b1[l];
    float b2o = b2[o];
    __syncthreads();
    for (int row = blockIdx.x * 4 + g; row < nrows; row += gridDim.x * 4) {
        if (l < FM) sx[g][l] = x[(size_t)row * FM + l];
        float acc = b1l;
#pragma unroll
        for (int k = 0; k < FM; k += 4) {
            float4 xv = *(const float4*)&sx[g][k];
            acc = fmaf(xv.x, sW1[(k + 0) * 64 + l], acc);
            acc = fmaf(xv.y, sW1[(k + 1) * 64 + l], acc);
            acc = fmaf(xv.z, sW1[(k + 2) * 64 + l], acc);
            acc = fmaf(xv.w, sW1[(k + 3) * 64 + l], acc);
        }
        sh[g][l] = fmaxf(acc, 0.0f);
        float y = 0.0f;
#pragma unroll
        for (int k = 0; k < 16; k += 4) {
            int kk = q * 16 + k;
            float4 hv = *(const float4*)&sh[g][kk];
            y = fmaf(hv.x, sW2[(kk + 0) * 16 + o], y);
            y = fmaf(hv.y, sW2[(kk + 1) * 16 + o], y);
            y = fmaf(hv.z, sW2[(kk + 2) * 16 + o], y);
            y = fmaf(hv.w, sW2[(kk + 3) * 16 + o], y);
        }
        y += __shfl_xor(y, 16);
        y += __shfl_xor(y, 32);
        if (q == 0) dst[(size_t)row * 16 + o] = 1.0f / (1.0f + expf(-(y + b2o)));
    }
}

// ---------------- launcher ----------------

extern "C" void kernel_launch(void* const* d_in, const int* in_sizes, int n_in,
                              void* d_out, int out_size, void* d_ws, size_t ws_size,
                              hipStream_t stream) {
    const int*   edge_var   = (const int*)d_in[0];
    const int*   edge_const = (const int*)d_in[1];
    const float* edge_val   = (const float*)d_in[2];
    const float* cond       = (const float*)d_in[3];
    const float* pc_W1 = (const float*)d_in[6];
    const float* pc_b1 = (const float*)d_in[7];
    const float* pc_W2 = (const float*)d_in[8];
    const float* pc_b2 = (const float*)d_in[9];
    const float* cu_W1 = (const float*)d_in[10];
    const float* cu_b1 = (const float*)d_in[11];
    const float* cu_W2 = (const float*)d_in[12];
    const float* cu_b2 = (const float*)d_in[13];
    const float* vu_W1 = (const float*)d_in[14];
    const float* vu_b1 = (const float*)d_in[15];
    const float* vu_W2 = (const float*)d_in[16];
    const float* vu_b2 = (const float*)d_in[17];
    const float* out_W1 = (const float*)d_in[18];
    const float* out_b1 = (const float*)d_in[19];
    const float* out_W2 = (const float*)d_in[20];
    const float* out_b2 = (const float*)d_in[21];

    float* ws = (float*)d_ws;
    size_t off = 0;
    auto alloc = [&](size_t nelems) {
        float* p = ws + off;
        off += (nelems + 15) & ~(size_t)15;
        return p;
    };
    float* emb    = alloc(CONST_COUNT * FM);
    float* cons   = alloc(CONST_COUNT * FM);
    float* vars   = alloc(VAR_COUNT * FM);
    float* msg    = alloc(VAR_COUNT * FM);
    int*   offs_c = (int*)alloc(CONST_COUNT + 1);
    int*   cur_c  = (int*)alloc(CONST_COUNT);
    int*   offs_v = (int*)alloc(VAR_COUNT + 1);
    int*   cur_v  = (int*)alloc(VAR_COUNT);
    int*   bsum_c = (int*)alloc(256);
    int*   bsum_v = (int*)alloc(256);
    int2*  csr_c  = (int2*)alloc((size_t)N_EDGES * 2);
    int2*  csr_v  = (int2*)alloc((size_t)N_EDGES * 2);
    size_t need_bytes = off * sizeof(float);
    bool fast = ws_size >= need_bytes;

    const int EB = (N_EDGES + 255) / 256;

    if (fast) {
        // Build CSR (sorted-by-destination edge lists), once per call.
        hipMemsetAsync(offs_c, 0, (CONST_COUNT + 1) * sizeof(int), stream);
        hipMemsetAsync(offs_v, 0, (VAR_COUNT + 1) * sizeof(int), stream);
        histo<<<EB, 256, 0, stream>>>(edge_var, edge_const, offs_v, offs_c, N_EDGES);
        int nb_c = (CONST_COUNT + 1023) / 1024;
        int nb_v = (VAR_COUNT + 1023) / 1024;
        scan1<<<nb_c, 256, 0, stream>>>(offs_c, offs_c, bsum_c, CONST_COUNT);
        scan1<<<nb_v, 256, 0, stream>>>(offs_v, offs_v, bsum_v, VAR_COUNT);
        scan2<<<1, 256, 0, stream>>>(bsum_c, nb_c);
        scan2<<<1, 256, 0, stream>>>(bsum_v, nb_v);
        scan3<<<(CONST_COUNT + 256) / 256 + 1, 256, 0, stream>>>(offs_c, cur_c, bsum_c,
                                                                 CONST_COUNT, N_EDGES);
        scan3<<<(VAR_COUNT + 256) / 256 + 1, 256, 0, stream>>>(offs_v, cur_v, bsum_v,
                                                               VAR_COUNT, N_EDGES);
        fill_csr<<<EB, 256, 0, stream>>>(edge_var, edge_const, edge_val,
                                         cur_c, cur_v, csr_c, csr_v, N_EDGES);
    }

    // variables = ones; emb = mlp_ln(conditions); constraints = emb
    fill_ones<<<(VAR_COUNT * FM + 255) / 256, 256, 0, stream>>>(vars, VAR_COUNT * FM);
    pc_mlp<<<1024, 256, 0, stream>>>(cond, pc_W1, pc_b1, pc_W2, pc_b2, emb, CONST_COUNT);
    hipMemcpyAsync(cons, emb, (size_t)CONST_COUNT * FM * sizeof(float),
                   hipMemcpyDeviceToDevice, stream);

    for (int pass = 0; pass < 3; ++pass) {
        if (fast) {
            seg_gather<<<(CONST_COUNT + 7) / 8, 256, 0, stream>>>(offs_c, csr_c, vars, msg,
                                                                  CONST_COUNT);
        } else {
            hipMemsetAsync(msg, 0, (size_t)CONST_COUNT * FM * sizeof(float), stream);
            scatter_edges<<<N_EDGES / 8, 256, 0, stream>>>(edge_var, edge_const, edge_val,
                                                           vars, msg, N_EDGES);
        }
        mlp_ln<3><<<1024, 256, 0, stream>>>(cons, emb, msg, cu_W1, cu_b1, cu_W2, cu_b2,
                                            cons, CONST_COUNT);
        if (fast) {
            seg_gather<<<(VAR_COUNT + 7) / 8, 256, 0, stream>>>(offs_v, csr_v, cons, msg,
                                                                VAR_COUNT);
        } else {
            hipMemsetAsync(msg, 0, (size_t)VAR_COUNT * FM * sizeof(float), stream);
            scatter_edges<<<N_EDGES / 8, 256, 0, stream>>>(edge_const, edge_var, edge_val,
                                                           cons, msg, N_EDGES);
        }
        mlp_ln<2><<<1024, 256, 0, stream>>>(vars, msg, nullptr, vu_W1, vu_b1, vu_W2, vu_b2,
                                            vars, VAR_COUNT);
    }

    out_mlp<<<1024, 256, 0, stream>>>(vars, out_W1, out_b1, out_W2, out_b2,
                                      (float*)d_out, VAR_COUNT);
}